// Round 23
// baseline (118.066 us; speedup 1.0000x reference)
//
#include <hip/hip_runtime.h>
#include <hip/hip_bf16.h>
#include <math.h>

#define B_ 8192
#define L_ 512
#define BL_ (B_ * L_)
#define KT_ 1536

using bf16x8 = __attribute__((ext_vector_type(8))) short;
using f32x4  = __attribute__((ext_vector_type(4))) float;

__device__ __forceinline__ float gelu_f(float v) {
    return 0.5f * v * (1.0f + erff(v * 0.70710678118654752f));
}
__device__ __forceinline__ unsigned short f2bf(float f) {
    unsigned int x = __float_as_uint(f);
    x += 0x7fffu + ((x >> 16) & 1u);   // RNE
    return (unsigned short)(x >> 16);
}
__device__ __forceinline__ void gload16(const void* g, void* l) {
    __builtin_amdgcn_global_load_lds(
        (const __attribute__((address_space(1))) unsigned int*)g,
        (__attribute__((address_space(3))) unsigned int*)l, 16, 0, 0);
}

// fused pre+prep: blocks [0,B_) = conv1+GELU -> h1, LayerNorm -> lnx (stride-256
// layout, conflict-free — R15-proven); blocks [B_,B_+1024) = weights + tables.
__global__ __launch_bounds__(256) void k_fused_pre(const float* __restrict__ x,
        const float* __restrict__ c1w, const float* __restrict__ c1b,
        const float* __restrict__ lg, const float* __restrict__ lbias,
        unsigned short* __restrict__ h1, unsigned short* __restrict__ lnx,
        const float* __restrict__ c3w, const float* __restrict__ w1,
        const float* __restrict__ w2, unsigned short* __restrict__ weff,
        unsigned short* __restrict__ w1b, unsigned short* __restrict__ w2b,
        float2* __restrict__ tab, float2* __restrict__ tab32) {
    const int tid = threadIdx.x;
    if (blockIdx.x >= B_) {
        // ---- prep path ----
        int idx = (blockIdx.x - B_) * 256 + tid;       // 512*512
        if (idx < 512) {
            double sv, cv;
            sincos((double)idx * (3.14159265358979323846 / 256.0), &sv, &cv);
            tab[idx] = make_float2((float)cv, (float)sv);
            if ((idx & 15) == 0) tab32[idx >> 4] = make_float2((float)cv, (float)sv);
        }
        int o = idx >> 9, i = idx & 511;
        const float* t = c3w + (size_t)idx * 3;
        float t0 = t[0], t1 = t[1], t2 = t[2];
        size_t base = (size_t)o * KT_ + i;
        weff[base]        = f2bf(0.25f * t0 + 0.5f * t1);
        weff[base + 512]  = f2bf(0.125f * t0 + 0.25f * t1 + 0.5f * t2);
        weff[base + 1024] = f2bf(0.125f * t1 + 0.25f * t2);
        w1b[idx] = f2bf(w1[idx]);
        w2b[idx] = f2bf(w2[idx]);
        return;
    }
    // ---- pre path (R15-proven stride-256 layout) ----
    __shared__ float xs[512];
    __shared__ float red[8];
    const long b = blockIdx.x;
    const float* xr = x + (b << 9);
    float x0 = xr[tid], x1 = xr[tid + 256];
    xs[tid] = x0; xs[tid + 256] = x1;
    float s = x0 + x1, ss = x0 * x0 + x1 * x1;
#pragma unroll
    for (int off = 32; off > 0; off >>= 1) {
        s += __shfl_xor(s, off);
        ss += __shfl_xor(ss, off);
    }
    if ((tid & 63) == 0) { red[tid >> 6] = s; red[4 + (tid >> 6)] = ss; }
    __syncthreads();
    s  = red[0] + red[1] + red[2] + red[3];
    ss = red[4] + red[5] + red[6] + red[7];
    const float mu = s * (1.f / 512.f);
    const float rs = rsqrtf(ss * (1.f / 512.f) - mu * mu + 1e-5f);
    float w[9], cb[3];
#pragma unroll
    for (int j = 0; j < 9; ++j) w[j] = c1w[j];
#pragma unroll
    for (int j = 0; j < 3; ++j) cb[j] = c1b[j];
#pragma unroll
    for (int half = 0; half < 2; ++half) {
        const int i = tid + (half << 8);
        const float xm = i ? xs[i - 1] : 0.f;
        const float xc = xs[i];
        const float xp = (i != 511) ? xs[i + 1] : 0.f;
        unsigned short* hb = h1 + b * KT_ + i;
#pragma unroll
        for (int c = 0; c < 3; ++c) {
            float v = w[c * 3] * xm + w[c * 3 + 1] * xc + w[c * 3 + 2] * xp + cb[c];
            hb[(long)c << 9] = f2bf(gelu_f(v));
        }
        lnx[(b << 9) + i] = f2bf(fmaf((xc - mu) * rs, lg[i], lbias[i]));
    }
}

// shared GEMM block body (single-buffer BK=64): C = A*W^T + sbias*bias
// LDS [*][64], slot-XOR swizzle slot^=(row&7), both-sides (rule #21).
__device__ __forceinline__ void gemm_body(
        const unsigned short* __restrict__ A, const unsigned short* __restrict__ W,
        const float* __restrict__ bias, float sbias,
        const float* __restrict__ xres, float* __restrict__ out0z,
        void* __restrict__ Cp, int KD, int emode, int m0, int n0,
        short As[128][64], short Bs[64][64]) {
    const int tid = threadIdx.x;
    const int lane = tid & 63;
    const int wid = tid >> 6;
    const int wm = (wid & 1) << 6;
    const int wn = (wid >> 1) << 5;
    f32x4 acc[4][2] = {};

    const int srow = tid >> 3;
    const int schunk = tid & 7;
    const unsigned short* Ab = A + (size_t)m0 * KD;
    const unsigned short* Wb = W + (size_t)n0 * KD;
    const int frow = lane & 15;
    const int fsw = frow & 7;
    const int s0 = lane >> 4;

    for (int k0 = 0; k0 < KD; k0 += 64) {
        __syncthreads();
#pragma unroll
        for (int seg = 0; seg < 4; ++seg) {
            const int r = (seg << 5) + srow;
            const int c = (schunk ^ (r & 7)) << 3;
            gload16(Ab + (size_t)r * KD + k0 + c, &As[r][schunk << 3]);
        }
#pragma unroll
        for (int seg = 0; seg < 2; ++seg) {
            const int r = (seg << 5) + srow;
            const int c = (schunk ^ (r & 7)) << 3;
            gload16(Wb + (size_t)r * KD + k0 + c, &Bs[r][schunk << 3]);
        }
        __syncthreads();
#pragma unroll
        for (int kk = 0; kk < 2; ++kk) {
            bf16x8 af[4], bfr[2];
            const int sl = (kk << 2) + s0;
#pragma unroll
            for (int m = 0; m < 4; ++m)
                af[m] = *(const bf16x8*)&As[wm + (m << 4) + frow][(sl ^ fsw) << 3];
#pragma unroll
            for (int n = 0; n < 2; ++n)
                bfr[n] = *(const bf16x8*)&Bs[wn + (n << 4) + frow][(sl ^ fsw) << 3];
#pragma unroll
            for (int m = 0; m < 4; ++m)
#pragma unroll
                for (int n = 0; n < 2; ++n)
                    acc[m][n] = __builtin_amdgcn_mfma_f32_16x16x32_bf16(af[m], bfr[n], acc[m][n], 0, 0, 0);
        }
    }

    const int col0 = n0 + wn + (lane & 15);
    const int rbase = m0 + wm + ((lane >> 4) << 2);
#pragma unroll
    for (int n = 0; n < 2; ++n) {
        const int col = col0 + (n << 4);
        const float bz = sbias * bias[col];
#pragma unroll
        for (int m = 0; m < 4; ++m) {
#pragma unroll
            for (int r = 0; r < 4; ++r) {
                const size_t row = rbase + (m << 4) + r;
                float v = acc[m][n][r] + bz;
                if (emode == 0) {
                    ((float*)Cp)[row * 512 + col] = v;
                } else if (emode == 1) {
                    ((unsigned short*)Cp)[row * 512 + col] = f2bf(gelu_f(v));
                } else {
                    ((float*)Cp)[row * 512 + col] = v + xres[row * 512 + col];
                    if (out0z) out0z[row * 512 + col] = 0.f;
                }
            }
        }
    }
}

template<int EMODE, int KD>
__global__ __launch_bounds__(256) void k_mgemm(
        const unsigned short* __restrict__ A, const unsigned short* __restrict__ W,
        const float* __restrict__ bias, float sbias,
        const float* __restrict__ xres, float* __restrict__ out0z,
        void* __restrict__ Cp) {
    __shared__ short As[128][64];
    __shared__ short Bs[64][64];
    gemm_body(A, W, bias, sbias, xres, out0z, Cp, KD, EMODE,
              blockIdx.x << 7, blockIdx.y << 6, As, Bs);
}

// mega: blocks [0,512) = trend GEMM; [512,1024) = MLP1
__global__ __launch_bounds__(256) void k_mega(
        const unsigned short* __restrict__ h1, const unsigned short* __restrict__ weff,
        const float* __restrict__ c3b, float* __restrict__ out2,
        const unsigned short* __restrict__ lnx, const unsigned short* __restrict__ w1b,
        const float* __restrict__ b1, unsigned short* __restrict__ m1) {
    __shared__ short As[128][64];
    __shared__ short Bs[64][64];
    int id = blockIdx.x;
    if (id < 512) {
        gemm_body(h1, weff, c3b, 0.875f, nullptr, nullptr, out2, KT_, 0,
                  (id & 63) << 7, (id >> 6) << 6, As, Bs);
    } else {
        id -= 512;
        gemm_body(lnx, w1b, b1, 1.0f, nullptr, nullptr, m1, 512, 1,
                  (id & 63) << 7, (id >> 6) << 6, As, Bs);
    }
}

// standalone season v7 (2 rows/block, fp32 stage1+stage2, packed-key top5;
// R17-proven at ~58 µs, conflicts 1.46M)
__global__ __launch_bounds__(256) void k_season(const float* __restrict__ x,
        const float2* __restrict__ gtab, const float2* __restrict__ gtab32,
        float* __restrict__ out1, float* __restrict__ out0z) {
    __shared__ float2 xp[2][256];
    __shared__ float2 tab[512];
    __shared__ float2 Ys[2][512];
    __shared__ unsigned long long wkey[2][4][5];
    __shared__ float2 wval[2][4][5];

    const int tid = threadIdx.x;
    const int w = tid >> 6, l = tid & 63;
    const long b = (long)blockIdx.x << 1;
    const float* xr0 = x + (b << 9);
    const float* xr1 = xr0 + 512;
    {
        const int t1s = tid >> 3, t0s = tid & 7;
        const int g = (t1s << 4) + t0s;
        xp[0][tid] = make_float2(xr0[g], xr0[g + 8]);
        xp[1][tid] = make_float2(xr1[g], xr1[g + 8]);
        tab[tid] = gtab[tid];
        tab[tid + 256] = gtab[tid + 256];
    }
    __syncthreads();

    const int rr = (w << 3) + (l & 7);
    const int t0 = l >> 3;
    float ra0 = 0.f, ia0 = 0.f, rb0 = 0.f, ib0 = 0.f;
    float ra1 = 0.f, ia1 = 0.f, rb1 = 0.f, ib1 = 0.f;
    int e32 = 0;
#pragma unroll
    for (int t1 = 0; t1 < 32; ++t1) {
        float2 wt = gtab32[e32];
        e32 = (e32 + rr) & 31;
        float2 v0 = xp[0][(t1 << 3) + t0];
        float2 v1 = xp[1][(t1 << 3) + t0];
        ra0 = fmaf(v0.x, wt.x, ra0); ia0 = fmaf(v0.x, wt.y, ia0);
        rb0 = fmaf(v0.y, wt.x, rb0); ib0 = fmaf(v0.y, wt.y, ib0);
        ra1 = fmaf(v1.x, wt.x, ra1); ia1 = fmaf(v1.x, wt.y, ia1);
        rb1 = fmaf(v1.y, wt.x, rb1); ib1 = fmaf(v1.y, wt.y, ib1);
    }
    Ys[0][(t0 << 5) + rr] = make_float2(ra0, -ia0);
    Ys[0][((t0 + 8) << 5) + rr] = make_float2(rb0, -ib0);
    Ys[1][(t0 << 5) + rr] = make_float2(ra1, -ia1);
    Ys[1][((t0 + 8) << 5) + rr] = make_float2(rb1, -ib1);

    const int k = ((l >> 3) << 5) + rr;
    float xre0 = 0.f, xim0 = 0.f, xre1 = 0.f, xim1 = 0.f;
    int e = 0;
#pragma unroll
    for (int t0i = 0; t0i < 16; ++t0i) {
        float2 y0 = Ys[0][(t0i << 5) + rr];
        float2 y1 = Ys[1][(t0i << 5) + rr];
        float2 wt = tab[e];
        e = (e + k) & 511;
        xre0 = fmaf(y0.x, wt.x, fmaf(y0.y, wt.y, xre0));
        xim0 = fmaf(y0.y, wt.x, fmaf(-y0.x, wt.y, xim0));
        xre1 = fmaf(y1.x, wt.x, fmaf(y1.y, wt.y, xre1));
        xim1 = fmaf(y1.y, wt.x, fmaf(-y1.x, wt.y, xim1));
    }
    unsigned long long key0 = 0, key1 = 0;
    if (k != 0) {
        float m0 = fmaf(xre0, xre0, xim0 * xim0);
        float m1 = fmaf(xre1, xre1, xim1 * xim1);
        key0 = ((unsigned long long)__float_as_uint(m0) << 32)
             | (unsigned long long)(4095 - k);
        key1 = ((unsigned long long)__float_as_uint(m1) << 32)
             | (unsigned long long)(4095 - k);
    }
    for (int rnd = 0; rnd < 5; ++rnd) {
        unsigned long long rk0 = key0, rk1 = key1;
#pragma unroll
        for (int off = 32; off > 0; off >>= 1) {
            unsigned long long o0 = __shfl_xor(rk0, off);
            unsigned long long o1 = __shfl_xor(rk1, off);
            rk0 = (o0 > rk0) ? o0 : rk0;
            rk1 = (o1 > rk1) ? o1 : rk1;
        }
        if (key0 == rk0 && rk0 != 0ull) {
            wkey[0][w][rnd] = rk0; wval[0][w][rnd] = make_float2(xre0, xim0); key0 = 0;
        }
        if (key1 == rk1 && rk1 != 0ull) {
            wkey[1][w][rnd] = rk1; wval[1][w][rnd] = make_float2(xre1, xim1); key1 = 0;
        }
    }
    __syncthreads();

#pragma unroll
    for (int rw = 0; rw < 2; ++rw) {
        float4 sel[5];
        int h0 = 0, h1i = 0, h2 = 0, h3 = 0;
#pragma unroll
        for (int rnd = 0; rnd < 5; ++rnd) {
            unsigned long long c0 = wkey[rw][0][h0], c1 = wkey[rw][1][h1i];
            unsigned long long c2 = wkey[rw][2][h2], c3 = wkey[rw][3][h3];
            unsigned long long bk = c0; int bw = 0;
            if (c1 > bk) { bk = c1; bw = 1; }
            if (c2 > bk) { bk = c2; bw = 2; }
            if (c3 > bk) { bk = c3; bw = 3; }
            const int hs = (bw == 0) ? h0 : (bw == 1) ? h1i : (bw == 2) ? h2 : h3;
            float2 v = wval[rw][bw][hs];
            h0 += (bw == 0); h1i += (bw == 1); h2 += (bw == 2); h3 += (bw == 3);
            const int kk = 4095 - (int)(bk & 0xFFFull);
            sel[rnd] = make_float4((float)kk, v.x, v.y, 0.f);
        }
        const long ro = ((b + rw) << 9);
#pragma unroll
        for (int half = 0; half < 2; ++half) {
            int t = tid + (half << 8);
            float acc = 0.f;
#pragma unroll
            for (int j = 0; j < 5; ++j) {
                float4 sj = sel[j];
                int kj = (int)sj.x;
                float2 wt = tab[(kj * t) & 511];
                acc += sj.y * wt.x - sj.z * wt.y;
            }
            out1[ro + t] = 2.f * acc;
            if (out0z) out0z[ro + t] = 0.f;
        }
    }
}

extern "C" void kernel_launch(void* const* d_in, const int* in_sizes, int n_in,
                              void* d_out, int out_size, void* d_ws, size_t ws_size,
                              hipStream_t stream) {
    const float* x   = (const float*)d_in[0];
    const float* c1w = (const float*)d_in[1];
    const float* c1b = (const float*)d_in[2];
    const float* c3w = (const float*)d_in[3];
    const float* c3b = (const float*)d_in[4];
    const float* w1  = (const float*)d_in[5];
    const float* b1  = (const float*)d_in[6];
    const float* w2  = (const float*)d_in[7];
    const float* b2  = (const float*)d_in[8];
    const float* lg  = (const float*)d_in[9];
    const float* lb  = (const float*)d_in[10];

    float* out  = (float*)d_out;
    float* out1 = out + (long)BL_;          // season
    float* out2 = out + 2L * BL_;           // trend
    float* out3 = out + 3L * BL_;           // e

    // d_ws layout: tab(4K)|tab32(256B)|pad to 16K | [h1 24M] [m1 8M] [w2b 0.5M]
    float2* tab   = (float2*)d_ws;
    float2* tab32 = (float2*)((char*)d_ws + 4096);
    const size_t H1B = 24u * 1024 * 1024, M1B = 8u * 1024 * 1024;
    const size_t W2B = 512 * 512 * 2;
    const bool ws_h1   = ws_size >= (size_t)16384 + H1B;
    const bool ws_full = ws_size >= (size_t)16384 + H1B + M1B + W2B;

    unsigned short* lnx = (unsigned short*)(out3);           // 8 MB in out3

    if (ws_h1) {
        unsigned short* h1 = (unsigned short*)((char*)d_ws + 16384);
        unsigned short* weff = (unsigned short*)d_out;       // 1.5 MB (dead after mega)
        unsigned short* w1b  = weff + (size_t)L_ * KT_;      // +0.5 MB (ends 2M)
        if (ws_full) {
            unsigned short* m1  = (unsigned short*)((char*)d_ws + 16384 + H1B);
            unsigned short* w2b = (unsigned short*)((char*)d_ws + 16384 + H1B + M1B);
            // 1) fused pre+prep: conv1+GELU -> h1, LN -> lnx, weights, tables
            k_fused_pre<<<B_ + 1024, 256, 0, stream>>>(x, c1w, c1b, lg, lb, h1, lnx,
                                                       c3w, w1, w2, weff, w1b, w2b,
                                                       tab, tab32);
            // 2) trend -> out2 || MLP1 -> m1
            k_mega<<<1024, 256, 0, stream>>>(h1, weff, c3b, out2, lnx, w1b, b1, m1);
            // 3) MLP2 -> out3 + zero out0 (weff/w1b dead; w2b safe in ws)
            k_mgemm<2, 512><<<dim3(64, 8), 256, 0, stream>>>(m1, w2b, b2, 1.0f,
                                                             x, out, out3);
            // 4) season -> out1 (no out0 duty)
            k_season<<<B_ / 2, 256, 0, stream>>>(x, tab, tab32, out1, nullptr);
        } else {
            unsigned short* w2b = w1b + (size_t)L_ * L_;     // ends 2.5M
            unsigned short* m1 = (unsigned short*)((char*)d_out + 8u * 1024 * 1024);
            k_fused_pre<<<B_ + 1024, 256, 0, stream>>>(x, c1w, c1b, lg, lb, h1, lnx,
                                                       c3w, w1, w2, weff, w1b, w2b,
                                                       tab, tab32);
            k_mgemm<0, KT_><<<dim3(64, 8), 256, 0, stream>>>(h1, weff, c3b, 0.875f,
                                                             nullptr, nullptr, out2);
            k_mgemm<1, 512><<<dim3(64, 8), 256, 0, stream>>>(lnx, w1b, b1, 1.0f,
                                                             nullptr, nullptr, m1);
            k_mgemm<2, 512><<<dim3(64, 8), 256, 0, stream>>>(m1, w2b, b2, 1.0f,
                                                             x, nullptr, out3);
            // season zeroes out0 (m1/w2b/weff/w1b in out0 all dead after MLP2)
            k_season<<<B_ / 2, 256, 0, stream>>>(x, tab, tab32, out1, out);
        }
    } else {
        // small-ws fallback: everything staged in d_out, season last with zero duty
        unsigned short* h1s = (unsigned short*)d_out;            // 24 MB [0,24M)
        unsigned short* weffS = h1s + (size_t)B_ * KT_;          // [24,25.5M)
        unsigned short* w1bS  = weffS + (size_t)L_ * KT_;
        unsigned short* w2bS  = w1bS + (size_t)L_ * L_;
        k_fused_pre<<<B_ + 1024, 256, 0, stream>>>(x, c1w, c1b, lg, lb, h1s, lnx,
                                                   c3w, w1, w2, weffS, w1bS, w2bS,
                                                   tab, tab32);
        k_mgemm<0, KT_><<<dim3(64, 8), 256, 0, stream>>>(h1s, weffS, c3b, 0.875f,
                                                         nullptr, nullptr, out2);
        unsigned short* m1 = (unsigned short*)d_out;             // [0,8M), h1 dead
        k_mgemm<1, 512><<<dim3(64, 8), 256, 0, stream>>>(lnx, w1bS, b1, 1.0f,
                                                         nullptr, nullptr, m1);
        k_mgemm<2, 512><<<dim3(64, 8), 256, 0, stream>>>(m1, w2bS, b2, 1.0f,
                                                         x, nullptr, out3);
        k_season<<<B_ / 2, 256, 0, stream>>>(x, tab, tab32, out1, out);
    }
}

// Round 24
// 111.371 us; speedup vs baseline: 1.0601x; 1.0601x over previous
//
#include <hip/hip_runtime.h>
#include <hip/hip_bf16.h>
#include <math.h>

#define B_ 8192
#define L_ 512
#define BL_ (B_ * L_)
#define KT_ 1536

using bf16x8 = __attribute__((ext_vector_type(8))) short;
using f32x4  = __attribute__((ext_vector_type(4))) float;

__device__ __forceinline__ float gelu_f(float v) {
    return 0.5f * v * (1.0f + erff(v * 0.70710678118654752f));
}
__device__ __forceinline__ unsigned short f2bf(float f) {
    unsigned int x = __float_as_uint(f);
    x += 0x7fffu + ((x >> 16) & 1u);   // RNE
    return (unsigned short)(x >> 16);
}
__device__ __forceinline__ void gload16(const void* g, void* l) {
    __builtin_amdgcn_global_load_lds(
        (const __attribute__((address_space(1))) unsigned int*)g,
        (__attribute__((address_space(3))) unsigned int*)l, 16, 0, 0);
}

// weight prep (1024 blocks): Weff bf16 (collapsed conv3+poly), w1/w2 -> bf16,
// + fp32 twiddle tables tab(512)/tab32(32)
__global__ __launch_bounds__(256) void k_prep(const float* __restrict__ c3w,
        const float* __restrict__ w1, const float* __restrict__ w2,
        unsigned short* __restrict__ weff, unsigned short* __restrict__ w1b,
        unsigned short* __restrict__ w2b,
        float2* __restrict__ tab, float2* __restrict__ tab32) {
    int idx = blockIdx.x * 256 + threadIdx.x;      // 512*512
    if (idx < 512) {
        double sv, cv;
        sincos((double)idx * (3.14159265358979323846 / 256.0), &sv, &cv);
        tab[idx] = make_float2((float)cv, (float)sv);
        if ((idx & 15) == 0) tab32[idx >> 4] = make_float2((float)cv, (float)sv);
    }
    int o = idx >> 9, i = idx & 511;
    const float* t = c3w + (size_t)idx * 3;
    float t0 = t[0], t1 = t[1], t2 = t[2];
    size_t base = (size_t)o * KT_ + i;
    weff[base]        = f2bf(0.25f * t0 + 0.5f * t1);
    weff[base + 512]  = f2bf(0.125f * t0 + 0.25f * t1 + 0.5f * t2);
    weff[base + 1024] = f2bf(0.125f * t1 + 0.25f * t2);
    w1b[idx] = f2bf(w1[idx]);
    w2b[idx] = f2bf(w2[idx]);
}

// fused pre(+season): 2 rows per block. Pre: conv1+GELU -> h1, LN -> lnx.
// Pre-loop positions STRIDED (i = tl + 128*j): consecutive lanes hit
// consecutive LDS addresses -> conflict-free. xp staged via global gather
// (L1-resident) + contiguous b64 LDS writes.
template<int DS>
__global__ __launch_bounds__(256) void k_preseason(const float* __restrict__ x,
        const float* __restrict__ c1w, const float* __restrict__ c1b,
        const float* __restrict__ lg, const float* __restrict__ lbias,
        unsigned short* __restrict__ h1, unsigned short* __restrict__ lnx,
        const float2* __restrict__ gtab, const float2* __restrict__ gtab32,
        float* __restrict__ out1, float* __restrict__ out0z) {
    __shared__ float xs[2][512];
    __shared__ float2 xp[2][256];   // p=8*t1+t0 -> (x[16t1+t0], x[16t1+t0+8])
    __shared__ float red[8];
    __shared__ float2 tab[512];
    __shared__ float2 Ys[2][512];
    __shared__ unsigned long long wkey[2][4][5];
    __shared__ float2 wval[2][4][5];

    const int tid = threadIdx.x;
    const int w = tid >> 6, l = tid & 63;
    const long b = (long)blockIdx.x << 1;              // rows b, b+1
    const int row = tid >> 7;                          // row team 0/1
    const int tl = tid & 127;
    const float* xr0 = x + (b << 9);
    const float* xr1 = xr0 + 512;

    // ---- staging ----
    const float* xr = x + ((b + row) << 9);
    float4 v4 = *(const float4*)(xr + (tl << 2));
    *(float4*)&xs[row][tl << 2] = v4;
    if (DS) {
        // xp: global gather (lines L1-resident) + contiguous b64 LDS writes
        const int t1s = tid >> 3, t0s = tid & 7;
        const int g = (t1s << 4) + t0s;
        xp[0][tid] = make_float2(xr0[g], xr0[g + 8]);
        xp[1][tid] = make_float2(xr1[g], xr1[g + 8]);
        tab[tid] = gtab[tid];
        tab[tid + 256] = gtab[tid + 256];
    }
    // LN stats partials (wave-level; each wave covers half a row)
    float s = v4.x + v4.y + v4.z + v4.w;
    float ss = v4.x * v4.x + v4.y * v4.y + v4.z * v4.z + v4.w * v4.w;
#pragma unroll
    for (int off = 32; off > 0; off >>= 1) {
        s += __shfl_xor(s, off);
        ss += __shfl_xor(ss, off);
    }
    if ((tid & 63) == 0) { red[w] = s; red[4 + w] = ss; }
    __syncthreads();                                   // barrier 1

    // ---- pre: conv1+GELU -> h1, LN -> lnx (4 strided positions/thread) ----
    {
        const float sr  = red[row * 2] + red[row * 2 + 1];
        const float ssr = red[4 + row * 2] + red[4 + row * 2 + 1];
        const float mu = sr * (1.f / 512.f);
        const float rs = rsqrtf(ssr * (1.f / 512.f) - mu * mu + 1e-5f);
        float w9[9], cb3[3];
#pragma unroll
        for (int j = 0; j < 9; ++j) w9[j] = c1w[j];
#pragma unroll
        for (int j = 0; j < 3; ++j) cb3[j] = c1b[j];
        unsigned short* hb = h1 + (b + row) * KT_;
        unsigned short* lr = lnx + ((b + row) << 9);
#pragma unroll
        for (int j = 0; j < 4; ++j) {
            const int i = tl + (j << 7);               // stride 128: lanes ->
            const float xm = i ? xs[row][i - 1] : 0.f; // consecutive LDS addrs
            const float xc = xs[row][i];
            const float xpv = (i != 511) ? xs[row][i + 1] : 0.f;
#pragma unroll
            for (int c = 0; c < 3; ++c) {
                float v = w9[c * 3] * xm + w9[c * 3 + 1] * xc + w9[c * 3 + 2] * xpv + cb3[c];
                hb[(c << 9) + i] = f2bf(gelu_f(v));
            }
            lr[i] = f2bf(fmaf((xc - mu) * rs, lg[i], lbias[i]));
        }
    }
    if (!DS) return;

    // ---- season v7 (identical arithmetic to prior rounds) ----
    const int rr = (w << 3) + (l & 7);
    const int t0 = l >> 3;
    float ra0 = 0.f, ia0 = 0.f, rb0 = 0.f, ib0 = 0.f;
    float ra1 = 0.f, ia1 = 0.f, rb1 = 0.f, ib1 = 0.f;
    int e32 = 0;
#pragma unroll
    for (int t1 = 0; t1 < 32; ++t1) {
        float2 wt = gtab32[e32];
        e32 = (e32 + rr) & 31;
        float2 v0 = xp[0][(t1 << 3) + t0];
        float2 v1 = xp[1][(t1 << 3) + t0];
        ra0 = fmaf(v0.x, wt.x, ra0); ia0 = fmaf(v0.x, wt.y, ia0);
        rb0 = fmaf(v0.y, wt.x, rb0); ib0 = fmaf(v0.y, wt.y, ib0);
        ra1 = fmaf(v1.x, wt.x, ra1); ia1 = fmaf(v1.x, wt.y, ia1);
        rb1 = fmaf(v1.y, wt.x, rb1); ib1 = fmaf(v1.y, wt.y, ib1);
    }
    Ys[0][(t0 << 5) + rr] = make_float2(ra0, -ia0);
    Ys[0][((t0 + 8) << 5) + rr] = make_float2(rb0, -ib0);
    Ys[1][(t0 << 5) + rr] = make_float2(ra1, -ia1);
    Ys[1][((t0 + 8) << 5) + rr] = make_float2(rb1, -ib1);

    const int k = ((l >> 3) << 5) + rr;
    float xre0 = 0.f, xim0 = 0.f, xre1 = 0.f, xim1 = 0.f;
    int e = 0;
#pragma unroll
    for (int t0i = 0; t0i < 16; ++t0i) {
        float2 y0 = Ys[0][(t0i << 5) + rr];
        float2 y1 = Ys[1][(t0i << 5) + rr];
        float2 wt = tab[e];
        e = (e + k) & 511;
        xre0 = fmaf(y0.x, wt.x, fmaf(y0.y, wt.y, xre0));
        xim0 = fmaf(y0.y, wt.x, fmaf(-y0.x, wt.y, xim0));
        xre1 = fmaf(y1.x, wt.x, fmaf(y1.y, wt.y, xre1));
        xim1 = fmaf(y1.y, wt.x, fmaf(-y1.x, wt.y, xim1));
    }

    unsigned long long key0 = 0, key1 = 0;
    if (k != 0) {
        float m0 = fmaf(xre0, xre0, xim0 * xim0);
        float m1 = fmaf(xre1, xre1, xim1 * xim1);
        key0 = ((unsigned long long)__float_as_uint(m0) << 32)
             | (unsigned long long)(4095 - k);
        key1 = ((unsigned long long)__float_as_uint(m1) << 32)
             | (unsigned long long)(4095 - k);
    }

    for (int rnd = 0; rnd < 5; ++rnd) {
        unsigned long long rk0 = key0, rk1 = key1;
#pragma unroll
        for (int off = 32; off > 0; off >>= 1) {
            unsigned long long o0 = __shfl_xor(rk0, off);
            unsigned long long o1 = __shfl_xor(rk1, off);
            rk0 = (o0 > rk0) ? o0 : rk0;
            rk1 = (o1 > rk1) ? o1 : rk1;
        }
        if (key0 == rk0 && rk0 != 0ull) {
            wkey[0][w][rnd] = rk0; wval[0][w][rnd] = make_float2(xre0, xim0); key0 = 0;
        }
        if (key1 == rk1 && rk1 != 0ull) {
            wkey[1][w][rnd] = rk1; wval[1][w][rnd] = make_float2(xre1, xim1); key1 = 0;
        }
    }
    __syncthreads();                                   // barrier 2

#pragma unroll
    for (int rw = 0; rw < 2; ++rw) {
        float4 sel[5];
        int h0 = 0, h1i = 0, h2 = 0, h3 = 0;
#pragma unroll
        for (int rnd = 0; rnd < 5; ++rnd) {
            unsigned long long c0 = wkey[rw][0][h0], c1 = wkey[rw][1][h1i];
            unsigned long long c2 = wkey[rw][2][h2], c3 = wkey[rw][3][h3];
            unsigned long long bk = c0; int bw = 0;
            if (c1 > bk) { bk = c1; bw = 1; }
            if (c2 > bk) { bk = c2; bw = 2; }
            if (c3 > bk) { bk = c3; bw = 3; }
            const int hs = (bw == 0) ? h0 : (bw == 1) ? h1i : (bw == 2) ? h2 : h3;
            float2 v = wval[rw][bw][hs];
            h0 += (bw == 0); h1i += (bw == 1); h2 += (bw == 2); h3 += (bw == 3);
            const int kk = 4095 - (int)(bk & 0xFFFull);
            sel[rnd] = make_float4((float)kk, v.x, v.y, 0.f);
        }
        const long ro = ((b + rw) << 9);
#pragma unroll
        for (int half = 0; half < 2; ++half) {
            int t = tid + (half << 8);
            float acc = 0.f;
#pragma unroll
            for (int j = 0; j < 5; ++j) {
                float4 sj = sel[j];
                int kj = (int)sj.x;
                float2 wt = tab[(kj * t) & 511];
                acc += sj.y * wt.x - sj.z * wt.y;
            }
            out1[ro + t] = 2.f * acc;
            if (out0z) out0z[ro + t] = 0.f;
        }
    }
}

// shared GEMM block body (single-buffer BK=64): C = A*W^T + sbias*bias
// LDS [*][64], slot-XOR swizzle slot^=(row&7), both-sides (rule #21).
__device__ __forceinline__ void gemm_body(
        const unsigned short* __restrict__ A, const unsigned short* __restrict__ W,
        const float* __restrict__ bias, float sbias,
        const float* __restrict__ xres, float* __restrict__ out0z,
        void* __restrict__ Cp, int KD, int emode, int m0, int n0,
        short As[128][64], short Bs[64][64]) {
    const int tid = threadIdx.x;
    const int lane = tid & 63;
    const int wid = tid >> 6;
    const int wm = (wid & 1) << 6;
    const int wn = (wid >> 1) << 5;
    f32x4 acc[4][2] = {};

    const int srow = tid >> 3;
    const int schunk = tid & 7;
    const unsigned short* Ab = A + (size_t)m0 * KD;
    const unsigned short* Wb = W + (size_t)n0 * KD;
    const int frow = lane & 15;
    const int fsw = frow & 7;
    const int s0 = lane >> 4;

    for (int k0 = 0; k0 < KD; k0 += 64) {
        __syncthreads();
#pragma unroll
        for (int seg = 0; seg < 4; ++seg) {
            const int r = (seg << 5) + srow;
            const int c = (schunk ^ (r & 7)) << 3;
            gload16(Ab + (size_t)r * KD + k0 + c, &As[r][schunk << 3]);
        }
#pragma unroll
        for (int seg = 0; seg < 2; ++seg) {
            const int r = (seg << 5) + srow;
            const int c = (schunk ^ (r & 7)) << 3;
            gload16(Wb + (size_t)r * KD + k0 + c, &Bs[r][schunk << 3]);
        }
        __syncthreads();
#pragma unroll
        for (int kk = 0; kk < 2; ++kk) {
            bf16x8 af[4], bfr[2];
            const int sl = (kk << 2) + s0;
#pragma unroll
            for (int m = 0; m < 4; ++m)
                af[m] = *(const bf16x8*)&As[wm + (m << 4) + frow][(sl ^ fsw) << 3];
#pragma unroll
            for (int n = 0; n < 2; ++n)
                bfr[n] = *(const bf16x8*)&Bs[wn + (n << 4) + frow][(sl ^ fsw) << 3];
#pragma unroll
            for (int m = 0; m < 4; ++m)
#pragma unroll
                for (int n = 0; n < 2; ++n)
                    acc[m][n] = __builtin_amdgcn_mfma_f32_16x16x32_bf16(af[m], bfr[n], acc[m][n], 0, 0, 0);
        }
    }

    const int col0 = n0 + wn + (lane & 15);
    const int rbase = m0 + wm + ((lane >> 4) << 2);
#pragma unroll
    for (int n = 0; n < 2; ++n) {
        const int col = col0 + (n << 4);
        const float bz = sbias * bias[col];
#pragma unroll
        for (int m = 0; m < 4; ++m) {
#pragma unroll
            for (int r = 0; r < 4; ++r) {
                const size_t row = rbase + (m << 4) + r;
                float v = acc[m][n][r] + bz;
                if (emode == 0) {
                    ((float*)Cp)[row * 512 + col] = v;
                } else if (emode == 1) {
                    ((unsigned short*)Cp)[row * 512 + col] = f2bf(gelu_f(v));
                } else {
                    ((float*)Cp)[row * 512 + col] = v + xres[row * 512 + col];
                    if (out0z) out0z[row * 512 + col] = 0.f;
                }
            }
        }
    }
}

template<int EMODE, int KD>
__global__ __launch_bounds__(256) void k_mgemm(
        const unsigned short* __restrict__ A, const unsigned short* __restrict__ W,
        const float* __restrict__ bias, float sbias,
        const float* __restrict__ xres, float* __restrict__ out0z,
        void* __restrict__ Cp) {
    __shared__ short As[128][64];
    __shared__ short Bs[64][64];
    gemm_body(A, W, bias, sbias, xres, out0z, Cp, KD, EMODE,
              blockIdx.x << 7, blockIdx.y << 6, As, Bs);
}

// mega: blocks [0,512) = trend GEMM; [512,1024) = MLP1
__global__ __launch_bounds__(256) void k_mega(
        const unsigned short* __restrict__ h1, const unsigned short* __restrict__ weff,
        const float* __restrict__ c3b, float* __restrict__ out2,
        const unsigned short* __restrict__ lnx, const unsigned short* __restrict__ w1b,
        const float* __restrict__ b1, unsigned short* __restrict__ m1) {
    __shared__ short As[128][64];
    __shared__ short Bs[64][64];
    int id = blockIdx.x;
    if (id < 512) {
        gemm_body(h1, weff, c3b, 0.875f, nullptr, nullptr, out2, KT_, 0,
                  (id & 63) << 7, (id >> 6) << 6, As, Bs);
    } else {
        id -= 512;
        gemm_body(lnx, w1b, b1, 1.0f, nullptr, nullptr, m1, 512, 1,
                  (id & 63) << 7, (id >> 6) << 6, As, Bs);
    }
}

// standalone season v7 (small-ws fallback; identical arithmetic)
__global__ __launch_bounds__(256) void k_season(const float* __restrict__ x,
        const float2* __restrict__ gtab, const float2* __restrict__ gtab32,
        float* __restrict__ out1, float* __restrict__ out0z) {
    __shared__ float2 xp[2][256];
    __shared__ float2 tab[512];
    __shared__ float2 Ys[2][512];
    __shared__ unsigned long long wkey[2][4][5];
    __shared__ float2 wval[2][4][5];

    const int tid = threadIdx.x;
    const int w = tid >> 6, l = tid & 63;
    const long b = (long)blockIdx.x << 1;
    const float* xr0 = x + (b << 9);
    const float* xr1 = xr0 + 512;
    {
        const int t1s = tid >> 3, t0s = tid & 7;
        const int g = (t1s << 4) + t0s;
        xp[0][tid] = make_float2(xr0[g], xr0[g + 8]);
        xp[1][tid] = make_float2(xr1[g], xr1[g + 8]);
        tab[tid] = gtab[tid];
        tab[tid + 256] = gtab[tid + 256];
    }
    __syncthreads();

    const int rr = (w << 3) + (l & 7);
    const int t0 = l >> 3;
    float ra0 = 0.f, ia0 = 0.f, rb0 = 0.f, ib0 = 0.f;
    float ra1 = 0.f, ia1 = 0.f, rb1 = 0.f, ib1 = 0.f;
    int e32 = 0;
#pragma unroll
    for (int t1 = 0; t1 < 32; ++t1) {
        float2 wt = gtab32[e32];
        e32 = (e32 + rr) & 31;
        float2 v0 = xp[0][(t1 << 3) + t0];
        float2 v1 = xp[1][(t1 << 3) + t0];
        ra0 = fmaf(v0.x, wt.x, ra0); ia0 = fmaf(v0.x, wt.y, ia0);
        rb0 = fmaf(v0.y, wt.x, rb0); ib0 = fmaf(v0.y, wt.y, ib0);
        ra1 = fmaf(v1.x, wt.x, ra1); ia1 = fmaf(v1.x, wt.y, ia1);
        rb1 = fmaf(v1.y, wt.x, rb1); ib1 = fmaf(v1.y, wt.y, ib1);
    }
    Ys[0][(t0 << 5) + rr] = make_float2(ra0, -ia0);
    Ys[0][((t0 + 8) << 5) + rr] = make_float2(rb0, -ib0);
    Ys[1][(t0 << 5) + rr] = make_float2(ra1, -ia1);
    Ys[1][((t0 + 8) << 5) + rr] = make_float2(rb1, -ib1);

    const int k = ((l >> 3) << 5) + rr;
    float xre0 = 0.f, xim0 = 0.f, xre1 = 0.f, xim1 = 0.f;
    int e = 0;
#pragma unroll
    for (int t0i = 0; t0i < 16; ++t0i) {
        float2 y0 = Ys[0][(t0i << 5) + rr];
        float2 y1 = Ys[1][(t0i << 5) + rr];
        float2 wt = tab[e];
        e = (e + k) & 511;
        xre0 = fmaf(y0.x, wt.x, fmaf(y0.y, wt.y, xre0));
        xim0 = fmaf(y0.y, wt.x, fmaf(-y0.x, wt.y, xim0));
        xre1 = fmaf(y1.x, wt.x, fmaf(y1.y, wt.y, xre1));
        xim1 = fmaf(y1.y, wt.x, fmaf(-y1.x, wt.y, xim1));
    }
    unsigned long long key0 = 0, key1 = 0;
    if (k != 0) {
        float m0 = fmaf(xre0, xre0, xim0 * xim0);
        float m1 = fmaf(xre1, xre1, xim1 * xim1);
        key0 = ((unsigned long long)__float_as_uint(m0) << 32)
             | (unsigned long long)(4095 - k);
        key1 = ((unsigned long long)__float_as_uint(m1) << 32)
             | (unsigned long long)(4095 - k);
    }
    for (int rnd = 0; rnd < 5; ++rnd) {
        unsigned long long rk0 = key0, rk1 = key1;
#pragma unroll
        for (int off = 32; off > 0; off >>= 1) {
            unsigned long long o0 = __shfl_xor(rk0, off);
            unsigned long long o1 = __shfl_xor(rk1, off);
            rk0 = (o0 > rk0) ? o0 : rk0;
            rk1 = (o1 > rk1) ? o1 : rk1;
        }
        if (key0 == rk0 && rk0 != 0ull) {
            wkey[0][w][rnd] = rk0; wval[0][w][rnd] = make_float2(xre0, xim0); key0 = 0;
        }
        if (key1 == rk1 && rk1 != 0ull) {
            wkey[1][w][rnd] = rk1; wval[1][w][rnd] = make_float2(xre1, xim1); key1 = 0;
        }
    }
    __syncthreads();

#pragma unroll
    for (int rw = 0; rw < 2; ++rw) {
        float4 sel[5];
        int h0 = 0, h1i = 0, h2 = 0, h3 = 0;
#pragma unroll
        for (int rnd = 0; rnd < 5; ++rnd) {
            unsigned long long c0 = wkey[rw][0][h0], c1 = wkey[rw][1][h1i];
            unsigned long long c2 = wkey[rw][2][h2], c3 = wkey[rw][3][h3];
            unsigned long long bk = c0; int bw = 0;
            if (c1 > bk) { bk = c1; bw = 1; }
            if (c2 > bk) { bk = c2; bw = 2; }
            if (c3 > bk) { bk = c3; bw = 3; }
            const int hs = (bw == 0) ? h0 : (bw == 1) ? h1i : (bw == 2) ? h2 : h3;
            float2 v = wval[rw][bw][hs];
            h0 += (bw == 0); h1i += (bw == 1); h2 += (bw == 2); h3 += (bw == 3);
            const int kk = 4095 - (int)(bk & 0xFFFull);
            sel[rnd] = make_float4((float)kk, v.x, v.y, 0.f);
        }
        const long ro = ((b + rw) << 9);
#pragma unroll
        for (int half = 0; half < 2; ++half) {
            int t = tid + (half << 8);
            float acc = 0.f;
#pragma unroll
            for (int j = 0; j < 5; ++j) {
                float4 sj = sel[j];
                int kj = (int)sj.x;
                float2 wt = tab[(kj * t) & 511];
                acc += sj.y * wt.x - sj.z * wt.y;
            }
            out1[ro + t] = 2.f * acc;
            if (out0z) out0z[ro + t] = 0.f;
        }
    }
}

__global__ __launch_bounds__(256) void k_zero(float4* __restrict__ p) {
    p[(long)blockIdx.x * 256 + threadIdx.x] = make_float4(0.f, 0.f, 0.f, 0.f);
}

extern "C" void kernel_launch(void* const* d_in, const int* in_sizes, int n_in,
                              void* d_out, int out_size, void* d_ws, size_t ws_size,
                              hipStream_t stream) {
    const float* x   = (const float*)d_in[0];
    const float* c1w = (const float*)d_in[1];
    const float* c1b = (const float*)d_in[2];
    const float* c3w = (const float*)d_in[3];
    const float* c3b = (const float*)d_in[4];
    const float* w1  = (const float*)d_in[5];
    const float* b1  = (const float*)d_in[6];
    const float* w2  = (const float*)d_in[7];
    const float* b2  = (const float*)d_in[8];
    const float* lg  = (const float*)d_in[9];
    const float* lb  = (const float*)d_in[10];

    float* out  = (float*)d_out;
    float* out1 = out + (long)BL_;          // season
    float* out2 = out + 2L * BL_;           // trend
    float* out3 = out + 3L * BL_;           // e

    // d_ws layout: tab(4K)|tab32(256B)|pad to 16K | [h1 24M] [m1 8M] [w2b 0.5M]
    float2* tab   = (float2*)d_ws;
    float2* tab32 = (float2*)((char*)d_ws + 4096);
    const size_t H1B = 24u * 1024 * 1024, M1B = 8u * 1024 * 1024;
    const size_t W2B = 512 * 512 * 2;
    const bool ws_h1   = ws_size >= (size_t)16384 + H1B;
    const bool ws_full = ws_size >= (size_t)16384 + H1B + M1B + W2B;

    unsigned short* lnx = (unsigned short*)(out3);           // 8 MB in out3

    if (ws_h1) {
        unsigned short* h1 = (unsigned short*)((char*)d_ws + 16384);
        unsigned short* weff = (unsigned short*)d_out;       // 1.5 MB (dead after mega)
        unsigned short* w1b  = weff + (size_t)L_ * KT_;      // +0.5 MB (ends 2M)
        if (ws_full) {
            unsigned short* m1  = (unsigned short*)((char*)d_ws + 16384 + H1B);
            unsigned short* w2b = (unsigned short*)((char*)d_ws + 16384 + H1B + M1B);
            k_prep<<<1024, 256, 0, stream>>>(c3w, w1, w2, weff, w1b, w2b, tab, tab32);
            k_preseason<1><<<B_ / 2, 256, 0, stream>>>(x, c1w, c1b, lg, lb, h1, lnx,
                                                       tab, tab32, out1, nullptr);
            // trend -> out2 || MLP1 -> m1
            k_mega<<<1024, 256, 0, stream>>>(h1, weff, c3b, out2, lnx, w1b, b1, m1);
            // MLP2 -> out3 + zero out0 (weff/w1b dead; w2b safe in ws)
            k_mgemm<2, 512><<<dim3(64, 8), 256, 0, stream>>>(m1, w2b, b2, 1.0f,
                                                             x, out, out3);
        } else {
            unsigned short* w2b = w1b + (size_t)L_ * L_;     // ends 2.5M
            unsigned short* m1 = (unsigned short*)((char*)d_out + 8u * 1024 * 1024);
            k_prep<<<1024, 256, 0, stream>>>(c3w, w1, w2, weff, w1b, w2b, tab, tab32);
            k_preseason<1><<<B_ / 2, 256, 0, stream>>>(x, c1w, c1b, lg, lb, h1, lnx,
                                                       tab, tab32, out1, nullptr);
            k_mgemm<0, KT_><<<dim3(64, 8), 256, 0, stream>>>(h1, weff, c3b, 0.875f,
                                                             nullptr, nullptr, out2);
            k_mgemm<1, 512><<<dim3(64, 8), 256, 0, stream>>>(lnx, w1b, b1, 1.0f,
                                                             nullptr, nullptr, m1);
            k_mgemm<2, 512><<<dim3(64, 8), 256, 0, stream>>>(m1, w2b, b2, 1.0f,
                                                             x, nullptr, out3);
            k_zero<<<4096, 256, 0, stream>>>((float4*)d_out);   // out0 = 0
        }
    } else {
        // small-ws fallback = R17 sequence (pre-only fused kernel, season last)
        unsigned short* h1s = (unsigned short*)d_out;            // 24 MB [0,24M)
        unsigned short* weffS = h1s + (size_t)B_ * KT_;          // [24,25.5M)
        unsigned short* w1bS  = weffS + (size_t)L_ * KT_;
        unsigned short* w2bS  = w1bS + (size_t)L_ * L_;
        k_prep<<<1024, 256, 0, stream>>>(c3w, w1, w2, weffS, w1bS, w2bS, tab, tab32);
        k_preseason<0><<<B_ / 2, 256, 0, stream>>>(x, c1w, c1b, lg, lb, h1s, lnx,
                                                   tab, tab32, out1, nullptr);
        k_mgemm<0, KT_><<<dim3(64, 8), 256, 0, stream>>>(h1s, weffS, c3b, 0.875f,
                                                         nullptr, nullptr, out2);
        unsigned short* m1 = (unsigned short*)d_out;             // [0,8M), h1 dead
        k_mgemm<1, 512><<<dim3(64, 8), 256, 0, stream>>>(lnx, w1bS, b1, 1.0f,
                                                         nullptr, nullptr, m1);
        k_mgemm<2, 512><<<dim3(64, 8), 256, 0, stream>>>(m1, w2bS, b2, 1.0f,
                                                         x, nullptr, out3);
        k_season<<<B_ / 2, 256, 0, stream>>>(x, tab, tab32, out1, out);
    }
}